// Round 1
// baseline (187.290 us; speedup 1.0000x reference)
//
#include <hip/hip_runtime.h>

// QuantizedActorMLP: x(1M,17) -> quant -> L1(17->64)+quantact -> L2(64->64)+quantact -> L3(64->6)
// Strategy: everything is on an int8 grid => exact integer arithmetic via bf16 MFMA
// (ints |n|<=127 exact in bf16; partial sums < 2^24 exact in fp32 accumulators).
// Transposed GEMMs D = W * H^T with W as A-operand; K-permutation of W2/W3 chosen so the
// C/D register layout of layer L IS the B-fragment layout of layer L+1 (pure register repack).

typedef __attribute__((ext_vector_type(8))) short short8;   // 8 x bf16 (4 VGPRs) MFMA A/B frag
typedef __attribute__((ext_vector_type(4))) float floatx4;  // MFMA C/D frag

// f32 integer (|v| <= 255) -> bf16 bits exactly: low 16 bits of f32 are zero.
__device__ __forceinline__ short bf16i(float v) {
  union { float f; unsigned u; } c; c.f = v;
  return (short)(c.u >> 16);
}

__global__ void __launch_bounds__(256) qmlp_fused(
    const float* __restrict__ x,
    const float* __restrict__ W1, const float* __restrict__ b1,
    const float* __restrict__ W2, const float* __restrict__ b2,
    const float* __restrict__ W3, const float* __restrict__ b3,
    float* __restrict__ out, int B)
{
  constexpr float QMAXF = 127.0f;
  constexpr float SCALE = 1.33f;
  const float step  = SCALE / QMAXF;   // matches fp32 'scale/QMAX' of reference
  const float istep = QMAXF / SCALE;

  __shared__ float red[256];
  __shared__ float sc_sh[3];
  const int tid = threadIdx.x;

  // ---- per-tensor weight scales s = max|W|/127 (redundant per block; W is 22KB, L2-resident) ----
  {
    float m = 0.f;
    for (int i = tid; i < 64 * 17; i += 256) m = fmaxf(m, fabsf(W1[i]));
    red[tid] = m; __syncthreads();
    for (int s = 128; s > 0; s >>= 1) { if (tid < s) red[tid] = fmaxf(red[tid], red[tid + s]); __syncthreads(); }
    if (tid == 0) sc_sh[0] = red[0] / QMAXF;
    __syncthreads();

    m = 0.f;
    for (int i = tid; i < 64 * 64; i += 256) m = fmaxf(m, fabsf(W2[i]));
    red[tid] = m; __syncthreads();
    for (int s = 128; s > 0; s >>= 1) { if (tid < s) red[tid] = fmaxf(red[tid], red[tid + s]); __syncthreads(); }
    if (tid == 0) sc_sh[1] = red[0] / QMAXF;
    __syncthreads();

    m = 0.f;
    for (int i = tid; i < 6 * 64; i += 256) m = fmaxf(m, fabsf(W3[i]));
    red[tid] = m; __syncthreads();
    for (int s = 128; s > 0; s >>= 1) { if (tid < s) red[tid] = fmaxf(red[tid], red[tid + s]); __syncthreads(); }
    if (tid == 0) sc_sh[2] = red[0] / QMAXF;
    __syncthreads();
  }
  const float s1 = sc_sh[0], s2 = sc_sh[1], s3 = sc_sh[2];

  const int lane = tid & 63;
  const int bi   = lane & 15;   // "16-dim" index: weight-row for A-frags, batch-row for B-frags/CD cols
  const int q    = lane >> 4;   // quad

  // ---- build weight fragments in registers (integer-valued bf16), once per block ----
  // A-frag (16x16x32): lane holds A[m=lane&15][k=8q+j], j=0..7.
  // L1: A1[m][k] = W1q[16t+m][k] (k<17 else 0), identity K order.
  short8 w1f[4];
  #pragma unroll
  for (int t = 0; t < 4; ++t) {
    #pragma unroll
    for (int j = 0; j < 8; ++j) {
      int k = 8 * q + j;
      float w = (k < 17) ? W1[(16 * t + bi) * 17 + k] : 0.f;
      float wi = rintf(w / s1);                          // IEEE div + RNE == jnp.round(w/s)
      wi = fminf(fmaxf(wi, -QMAXF), QMAXF);
      w1f[t][j] = bf16i(wi);
    }
  }
  // L2/L3 K-permutation: B-frag slot (s,q,j) is fed by C-slot (t=2s+(j>>2), r=j&3) holding
  // neuron 16t+4q+r => A[m][kappa=32s+8q+j] = W[m][eta], eta = 32s+16(j>>2)+4q+(j&3).
  short8 w2f[4][2];
  #pragma unroll
  for (int t = 0; t < 4; ++t) {
    #pragma unroll
    for (int s = 0; s < 2; ++s) {
      #pragma unroll
      for (int j = 0; j < 8; ++j) {
        int eta = 32 * s + 16 * (j >> 2) + 4 * q + (j & 3);
        float w = W2[(16 * t + bi) * 64 + eta];
        float wi = rintf(w / s2);
        wi = fminf(fmaxf(wi, -QMAXF), QMAXF);
        w2f[t][s][j] = bf16i(wi);
      }
    }
  }
  short8 w3f[2];
  #pragma unroll
  for (int s = 0; s < 2; ++s) {
    #pragma unroll
    for (int j = 0; j < 8; ++j) {
      int eta = 32 * s + 16 * (j >> 2) + 4 * q + (j & 3);
      float w = (bi < 6) ? W3[bi * 64 + eta] : 0.f;
      float wi = rintf(w / s3);
      wi = fminf(fmaxf(wi, -QMAXF), QMAXF);
      w3f[s][j] = bf16i(wi);
    }
  }

  // ---- per-slot biases (C-slot (t,r) of lane-quad q is neuron 16t+4q+r) ----
  // Hidden epilogues work in "integer units": z = acc*g + bias*istep, clamp +-127, rint.
  const float g1 = (s1 * step) * istep;
  const float g2 = (s2 * step) * istep;
  const float sc3 = s3 * step;
  float b1s[4][4], b2s[4][4], b3s[4];
  #pragma unroll
  for (int t = 0; t < 4; ++t) {
    #pragma unroll
    for (int r = 0; r < 4; ++r) {
      b1s[t][r] = b1[16 * t + 4 * q + r] * istep;
      b2s[t][r] = b2[16 * t + 4 * q + r] * istep;
    }
  }
  #pragma unroll
  for (int r = 0; r < 4; ++r) {
    int n = 4 * q + r;
    b3s[r] = (n < 6) ? b3[n] : 0.f;
  }

  // ---- row loop: each wave processes 16 batch rows per iteration ----
  const int wave_id = (int)((blockIdx.x * blockDim.x + tid) >> 6);
  const int nwaves  = (int)((gridDim.x * blockDim.x) >> 6);
  const int ntiles  = B >> 4;
  const floatx4 zero4 = {0.f, 0.f, 0.f, 0.f};

  for (int tile = wave_id; tile < ntiles; tile += nwaves) {
    const size_t row = (size_t)tile * 16 + bi;
    const float* xr = x + row * 17;

    // input quant -> B-frag of X^T: lane holds Xq[row=bi][k=8q+j]
    short8 af;
    #pragma unroll
    for (int j = 0; j < 8; ++j) {
      int k = 8 * q + j;
      float xv = (k < 17) ? xr[k] : 0.f;
      float a = rintf(fminf(fmaxf(xv * istep, -QMAXF), QMAXF));
      af[j] = bf16i(a);
    }

    // L1: D1 = W1q * Xq^T (4 M-tiles of neurons)
    floatx4 c1[4];
    #pragma unroll
    for (int t = 0; t < 4; ++t)
      c1[t] = __builtin_amdgcn_mfma_f32_16x16x32_bf16(w1f[t], af, zero4, 0, 0, 0);

    // epilogue 1: integer-unit rescale + hardtanh-quant -> h1 B-frags (pure register repack)
    short8 h1[2];
    #pragma unroll
    for (int t = 0; t < 4; ++t) {
      #pragma unroll
      for (int r = 0; r < 4; ++r) {
        float z = fmaf(c1[t][r], g1, b1s[t][r]);
        z = rintf(fminf(fmaxf(z, -QMAXF), QMAXF));
        h1[t >> 1][(t & 1) * 4 + r] = bf16i(z);
      }
    }

    // L2: D2 = W2q(perm) * H1^T, K=64 (2 K-steps)
    floatx4 c2[4];
    #pragma unroll
    for (int t = 0; t < 4; ++t) {
      c2[t] = __builtin_amdgcn_mfma_f32_16x16x32_bf16(w2f[t][0], h1[0], zero4, 0, 0, 0);
      c2[t] = __builtin_amdgcn_mfma_f32_16x16x32_bf16(w2f[t][1], h1[1], c2[t], 0, 0, 0);
    }

    short8 h2[2];
    #pragma unroll
    for (int t = 0; t < 4; ++t) {
      #pragma unroll
      for (int r = 0; r < 4; ++r) {
        float z = fmaf(c2[t][r], g2, b2s[t][r]);
        z = rintf(fminf(fmaxf(z, -QMAXF), QMAXF));
        h2[t >> 1][(t & 1) * 4 + r] = bf16i(z);
      }
    }

    // L3: D3 = W3q(perm, rows 6..15 zero) * H2^T
    floatx4 c3;
    c3 = __builtin_amdgcn_mfma_f32_16x16x32_bf16(w3f[0], h2[0], zero4, 0, 0, 0);
    c3 = __builtin_amdgcn_mfma_f32_16x16x32_bf16(w3f[1], h2[1], c3, 0, 0, 0);

    // epilogue 3 + store: lane (q,bi) holds out[row=bi][neuron=4q+r]; only neurons 0..5 stored.
    float o0 = fmaf(c3[0], sc3, b3s[0]);
    float o1 = fmaf(c3[1], sc3, b3s[1]);
    float o2 = fmaf(c3[2], sc3, b3s[2]);
    float o3 = fmaf(c3[3], sc3, b3s[3]);
    float* orow = out + row * 6;           // 24B rows: all stores 8B-aligned
    if (q == 0) {
      *(float2*)(orow)     = make_float2(o0, o1);
      *(float2*)(orow + 2) = make_float2(o2, o3);
    } else if (q == 1) {
      *(float2*)(orow + 4) = make_float2(o0, o1);
    }
  }
}

extern "C" void kernel_launch(void* const* d_in, const int* in_sizes, int n_in,
                              void* d_out, int out_size, void* d_ws, size_t ws_size,
                              hipStream_t stream) {
  const float* x  = (const float*)d_in[0];
  const float* W1 = (const float*)d_in[1];
  const float* b1 = (const float*)d_in[2];
  const float* W2 = (const float*)d_in[3];
  const float* b2 = (const float*)d_in[4];
  const float* W3 = (const float*)d_in[5];
  const float* b3 = (const float*)d_in[6];
  float* out = (float*)d_out;
  const int B = in_sizes[0] / 17;          // 1048576

  dim3 grid(1024), block(256);             // 4096 waves -> 16 row-tiles each
  qmlp_fused<<<grid, block, 0, stream>>>(x, W1, b1, W2, b2, W3, b3, out, B);
}